// Round 10
// baseline (71.174 us; speedup 1.0000x reference)
//
#include <hip/hip_runtime.h>

// Problem geometry (fixed by the reference): u is (B=2, C=3, D=160, H=192, W=160) float32.
#define Dd 160
#define Hh 192
#define Ww 160
#define HW (Hh * Ww)                       // 30720
#define DHW ((size_t)Dd * HW)              // 4,915,200
#define NVOX_D 9830400.0                   // 2 * 160*192*160

#define TH 8                                // h-rows per block
#define TD 10                               // d-planes per block (sliding window)
#define QROW (Ww / 4)                       // 40 float4-quads per row
#define TPB (QROW * TH)                     // 320 threads = 5 waves
#define NHT (Hh / TH)                       // 24
#define NDS (Dd / TD)                       // 16
#define GRID1 (2 * NHT * NDS)               // 768 blocks
#define NXCD 8
#define CHUNK (GRID1 / NXCD)                // 96 logical blocks per XCD
#define NWAVE (TPB / 64)                    // 5
#define BLK2 256

__device__ __forceinline__ float4 ld4(const float* p) {
    return *reinterpret_cast<const float4*>(p);
}

__device__ __forceinline__ int clampi(int v, int lo, int hi) {
    return (v < lo) ? lo : ((v > hi) ? hi : v);
}

// w-gradient for a quad given its left/right edge scalars (jnp.gradient semantics)
__device__ __forceinline__ float4 wgrad(float4 cc, float lft, float rgt, int w0) {
    float4 g;
    g.x = (w0 == 0)      ? (cc.y - cc.x) : 0.5f * (cc.y - lft);
    g.y = 0.5f * (cc.z - cc.x);
    g.z = 0.5f * (cc.w - cc.y);
    g.w = (w0 + 4 == Ww) ? (cc.w - cc.z) : 0.5f * (rgt - cc.z);
    return g;
}

// relu(-det(J)) for one voxel given the 9 raw (unscaled) finite-difference grads.
__device__ __forceinline__ float relu_negdet(
    float gd0, float gh0, float gw0,
    float gd1, float gh1, float gw1,
    float gd2, float gh2, float gw2)
{
    const float sx = 79.5f;   // (D-1)/2 -> channel 0
    const float sy = 95.5f;   // (H-1)/2 -> channel 1
    const float sz = 79.5f;   // (W-1)/2 -> channel 2
    float dxx = fmaf(sx, gd0, 1.0f);
    float dxy = sx * gh0;
    float dxz = sx * gw0;
    float dyx = sy * gd1;
    float dyy = fmaf(sy, gh1, 1.0f);
    float dyz = sy * gw1;
    float dzx = sz * gd2;
    float dzy = sz * gh2;
    float dzz = fmaf(sz, gw2, 1.0f);
    float det = dxx * (dyy * dzz - dyz * dzy)
              + dxy * (dyz * dzx - dyx * dzz)
              + dxz * (dyx * dzy - dyy * dzx);
    return fmaxf(-det, 0.0f);
}

// Register-pipelined d-march: step i computes plane d ENTIRELY from registers
// loaded at step i-1 (or the prologue), and issues step i+1's loads up front.
// No load is consumed in the step it was issued -> each load has a full step
// of own-wave compute (x 10 co-resident waves) to cover L2/L3/HBM latency.
__global__ __launch_bounds__(TPB, 3) void jac_partial(const float* __restrict__ u,
                                                      float* __restrict__ part)
{
    // bijective XCD-chunked swizzle (768 = 8*96, ds fastest): d-neighbors same XCD
    const int lg  = (blockIdx.x % NXCD) * CHUNK + blockIdx.x / NXCD;
    const int ds  = lg % NDS;
    const int ht  = (lg / NDS) % NHT;
    const int b   = lg / (NDS * NHT);

    const int tid = threadIdx.x;
    const int wq  = tid % QROW;
    const int hh  = tid / QROW;
    const int h   = ht * TH + hh;
    const int w0  = wq * 4;

    // jnp.gradient edge handling via clamped indices (one-sided at h=0/H-1)
    const int hm = (h > 0)      ? h - 1 : 0;
    const int hp = (h < Hh - 1) ? h + 1 : Hh - 1;
    const float hinv = 1.0f / (float)(hp - hm);
    const int offm = (hm - h) * Ww;   // 0 or -Ww
    const int offp = (hp - h) * Ww;   // 0 or +Ww

    const int d0     = ds * TD;
    const int dir    = (ds & 1) ? -1 : 1;              // boustrophedon
    const int dstart = (dir > 0) ? d0 : d0 + TD - 1;

    // channel base pointers at (b, c, d=0, h, w0)
    const float* pcA = u + (size_t)(b * 3 + 0) * DHW + (size_t)h * Ww + w0;
    const float* pcB = pcA + DHW;
    const float* pcC = pcA + 2 * DHW;

    // ---- pipeline state (all consumed one step after load) ----
    float4 a0, a1, a2, b0, b1, b2, c0, c1, c2;      // center planes d-1, d, d+1
    float4 rAm, rAp, rBm, rBp, rCm, rCp;            // h-neighbor rows at plane d
    float  lA, rA, lB, rB, lC, rC;                  // w-edge scalars at plane d

    // prologue: fill the whole step-0 state
    {
        const size_t om = (size_t)clampi(dstart - dir, 0, Dd - 1) * HW;
        const size_t oc = (size_t)dstart * HW;
        const size_t of = (size_t)clampi(dstart + dir, 0, Dd - 1) * HW;
        a0 = ld4(pcA + om);  a1 = ld4(pcA + oc);  a2 = ld4(pcA + of);
        b0 = ld4(pcB + om);  b1 = ld4(pcB + oc);  b2 = ld4(pcB + of);
        c0 = ld4(pcC + om);  c1 = ld4(pcC + oc);  c2 = ld4(pcC + of);
        rAm = ld4(pcA + oc + offm);  rAp = ld4(pcA + oc + offp);
        rBm = ld4(pcB + oc + offm);  rBp = ld4(pcB + oc + offp);
        rCm = ld4(pcC + oc + offm);  rCp = ld4(pcC + oc + offp);
        lA = (w0 > 0) ? (pcA + oc)[-1] : 0.0f;
        lB = (w0 > 0) ? (pcB + oc)[-1] : 0.0f;
        lC = (w0 > 0) ? (pcC + oc)[-1] : 0.0f;
        rA = (w0 + 4 < Ww) ? (pcA + oc)[4] : 0.0f;
        rB = (w0 + 4 < Ww) ? (pcB + oc)[4] : 0.0f;
        rC = (w0 + 4 < Ww) ? (pcC + oc)[4] : 0.0f;
    }

    float acc = 0.0f;

    #pragma unroll 2
    for (int i = 0; i < TD; ++i) {
        const int d = dstart + dir * i;
        const float dinvs = (float)dir * ((d > 0 && d < Dd - 1) ? 0.5f : 1.0f);

        // ---- issue ALL of step i+1's loads first (consumed next iteration) ----
        float4 na2, nb2, nc2, nrAm, nrAp, nrBm, nrBp, nrCm, nrCp;
        float  nlA, nrA, nlB, nrB, nlC, nrC;
        const bool more = (i < TD - 1);
        if (more) {
            const int dn = d + dir;                         // next compute plane (in range)
            const size_t on  = (size_t)dn * HW;
            const size_t onn = (size_t)clampi(dn + dir, 0, Dd - 1) * HW;
            na2 = ld4(pcA + onn);  nb2 = ld4(pcB + onn);  nc2 = ld4(pcC + onn);
            nrAm = ld4(pcA + on + offm);  nrAp = ld4(pcA + on + offp);
            nrBm = ld4(pcB + on + offm);  nrBp = ld4(pcB + on + offp);
            nrCm = ld4(pcC + on + offm);  nrCp = ld4(pcC + on + offp);
            nlA = (w0 > 0) ? (pcA + on)[-1] : 0.0f;
            nlB = (w0 > 0) ? (pcB + on)[-1] : 0.0f;
            nlC = (w0 > 0) ? (pcC + on)[-1] : 0.0f;
            nrA = (w0 + 4 < Ww) ? (pcA + on)[4] : 0.0f;
            nrB = (w0 + 4 < Ww) ? (pcB + on)[4] : 0.0f;
            nrC = (w0 + 4 < Ww) ? (pcC + on)[4] : 0.0f;
        }

        // ---- compute plane d purely from registers ----
        float4 gwA = wgrad(a1, lA, rA, w0);
        float4 gwB = wgrad(b1, lB, rB, w0);
        float4 gwC = wgrad(c1, lC, rC, w0);

        float4 ghA = make_float4((rAp.x - rAm.x) * hinv, (rAp.y - rAm.y) * hinv,
                                 (rAp.z - rAm.z) * hinv, (rAp.w - rAm.w) * hinv);
        float4 ghB = make_float4((rBp.x - rBm.x) * hinv, (rBp.y - rBm.y) * hinv,
                                 (rBp.z - rBm.z) * hinv, (rBp.w - rBm.w) * hinv);
        float4 ghC = make_float4((rCp.x - rCm.x) * hinv, (rCp.y - rCm.y) * hinv,
                                 (rCp.z - rCm.z) * hinv, (rCp.w - rCm.w) * hinv);

        float4 gdA = make_float4((a2.x - a0.x) * dinvs, (a2.y - a0.y) * dinvs,
                                 (a2.z - a0.z) * dinvs, (a2.w - a0.w) * dinvs);
        float4 gdB = make_float4((b2.x - b0.x) * dinvs, (b2.y - b0.y) * dinvs,
                                 (b2.z - b0.z) * dinvs, (b2.w - b0.w) * dinvs);
        float4 gdC = make_float4((c2.x - c0.x) * dinvs, (c2.y - c0.y) * dinvs,
                                 (c2.z - c0.z) * dinvs, (c2.w - c0.w) * dinvs);

        acc += relu_negdet(gdA.x, ghA.x, gwA.x, gdB.x, ghB.x, gwB.x, gdC.x, ghC.x, gwC.x)
             + relu_negdet(gdA.y, ghA.y, gwA.y, gdB.y, ghB.y, gwB.y, gdC.y, ghC.y, gwC.y)
             + relu_negdet(gdA.z, ghA.z, gwA.z, gdB.z, ghB.z, gwB.z, gdC.z, ghC.z, gwC.z)
             + relu_negdet(gdA.w, ghA.w, gwA.w, gdB.w, ghB.w, gwB.w, gdC.w, ghC.w, gwC.w);

        // ---- slide the pipeline ----
        if (more) {
            a0 = a1; a1 = a2; a2 = na2;
            b0 = b1; b1 = b2; b2 = nb2;
            c0 = c1; c1 = c2; c2 = nc2;
            rAm = nrAm; rAp = nrAp; rBm = nrBm; rBp = nrBp; rCm = nrCm; rCp = nrCp;
            lA = nlA; rA = nrA; lB = nlB; rB = nrB; lC = nlC; rC = nrC;
        }
    }

    // deterministic block reduction: wave64 shuffle tree, then 5-word LDS
    #pragma unroll
    for (int off = 32; off > 0; off >>= 1)
        acc += __shfl_down(acc, off, 64);
    __shared__ float sred[NWAVE];
    const int lane = tid & 63;
    const int wid  = tid >> 6;
    if (lane == 0) sred[wid] = acc;
    __syncthreads();
    if (tid == 0)
        part[lg] = ((sred[0] + sred[1]) + (sred[2] + sred[3])) + sred[4];
}

// 768 partials -> mean. 3 independent loads per thread, f64 fixed-tree reduce
// (deterministic; f64 kills the ~2e8-magnitude sum's rounding concern).
__global__ __launch_bounds__(BLK2) void jac_final(const float* __restrict__ part,
                                                  float* __restrict__ out)
{
    const int t = threadIdx.x;
    double a = (double)part[t] + (double)part[t + 256] + (double)part[t + 512];
    __shared__ double s[BLK2];
    s[t] = a;
    __syncthreads();
    #pragma unroll
    for (int off = BLK2 / 2; off > 0; off >>= 1) {
        if (t < off) s[t] += s[t + off];
        __syncthreads();
    }
    if (t == 0)
        out[0] = (float)(s[0] / NVOX_D);
}

extern "C" void kernel_launch(void* const* d_in, const int* in_sizes, int n_in,
                              void* d_out, int out_size, void* d_ws, size_t ws_size,
                              hipStream_t stream)
{
    const float* u = (const float*)d_in[0];
    float* part = (float*)d_ws;              // 768 floats = 3 KB of scratch

    jac_partial<<<GRID1, TPB, 0, stream>>>(u, part);
    jac_final<<<1, BLK2, 0, stream>>>(part, (float*)d_out);
}